// Round 13
// baseline (334.814 us; speedup 1.0000x reference)
//
#include <hip/hip_runtime.h>
#include <hip/hip_bf16.h>

#define NN 100000
#define NE 1200000
#define NE4 (NE / 4)                         // 300000
#define XCD_N 8
#define NPX (NN / XCD_N)                     // 12500 nodes per XCD
#define CAP 32                               // bucket capacity (P(deg>32) ~ 3e-7/node; spill covers)
#define SPILL_MAX 4096
#define NBLK_A ((NE4 + 255) / 256)           // 1172 phase-A blocks (disjoint stripes)
#define QCAP2 224                            // per-(block,bin) queue cap (mu=128, sigma=10.6 -> 9 sigma)
#define PSPILL_MAX 8192

typedef float floatx2 __attribute__((ext_vector_type(2)));

// ---------------- build phase A: stripe -> LDS bins by owner-XCD -> coalesced queue flush ----
// Port law (R9): random-miss service is ~126 GB/s per XCD; R6's one-pass build made every
// XCD stream the whole 9.6MB edge list (~78us). Here each block reads a DISJOINT stripe
// once (1.2MB/XCD aggregate) and bins edges by owner q = dst/NPX into LDS (LDS atomics
// only -- R10's global ballot-atomic scheme was latency-bound at 111us; this avoids it).
// Each bin is flushed coalesced to region [block][q], written by exactly one block ->
// single-XCD dirty lines, evict once (R3 lesson). Overflow (9-sigma padded) -> pspill.
__global__ __launch_bounds__(256) void part2_kernel(const int* __restrict__ esrc,
                                                    const int* __restrict__ edst,
                                                    uint2* __restrict__ queue,
                                                    int* __restrict__ qcnt,
                                                    uint2* __restrict__ pspill,
                                                    int* __restrict__ pspill_cnt) {
    __shared__ int lcnt[8];
    __shared__ uint2 bins[8][QCAP2];
    int tid = threadIdx.x;
    if (tid < 8) lcnt[tid] = 0;
    __syncthreads();
    int i = blockIdx.x * 256 + tid;                   // one int4 per thread, disjoint stripes
    if (i < NE4) {
        int4 d = ((const int4*)edst)[i];
        int4 s = ((const int4*)esrc)[i];
        #pragma unroll
        for (int c = 0; c < 4; ++c) {
            int dd = (c == 0) ? d.x : (c == 1) ? d.y : (c == 2) ? d.z : d.w;
            int ss = (c == 0) ? s.x : (c == 1) ? s.y : (c == 2) ? s.z : s.w;
            int q = dd / NPX;
            int slot = atomicAdd(&lcnt[q], 1);        // LDS atomic: no global round-trip
            if (slot < QCAP2) bins[q][slot] = make_uint2((unsigned)dd, (unsigned)ss);
            else {
                int p = atomicAdd(pspill_cnt, 1);
                if (p < PSPILL_MAX) pspill[p] = make_uint2((unsigned)dd, (unsigned)ss);
            }
        }
    }
    __syncthreads();
    // coalesced flush: bin q -> queue[(block*8+q)*QCAP2 ...]
    for (int idx = tid; idx < 8 * QCAP2; idx += 256) {
        int q = idx / QCAP2, j = idx - q * QCAP2;
        int c = lcnt[q]; if (c > QCAP2) c = QCAP2;
        if (j < c) queue[((size_t)blockIdx.x * 8 + q) * QCAP2 + j] = bins[q][j];
    }
    if (tid < 8) {
        int c = lcnt[tid];
        qcnt[blockIdx.x * 8 + tid] = c > QCAP2 ? QCAP2 : c;
    }
}

// ---------------- build phase B: owner XCD drains its bins into deg/bucket ----------------
// blocks: owner q = blockIdx&7 (round-robin XCD mapping, normal dispatch only -- R5:
// coop launch breaks it), sub = blockIdx>>3 walks source blocks. Reads ~1.2MB/XCD
// streaming; deg/bucket lines owned by this XCD (single-writer-XCD, R3/R4 lesson).
__global__ __launch_bounds__(256) void fill2_kernel(const uint2* __restrict__ queue,
                                                    const int* __restrict__ qcnt,
                                                    const uint2* __restrict__ pspill,
                                                    const int* __restrict__ pspill_cnt,
                                                    int* __restrict__ deg,
                                                    int* __restrict__ bucket,
                                                    int* __restrict__ spill,
                                                    int* __restrict__ spill_cnt) {
    int q = blockIdx.x & 7;
    int sub = blockIdx.x >> 3;                        // 0..255
    int tid = threadIdx.x;
    for (int b = sub; b < NBLK_A; b += 256) {
        int cnt = qcnt[b * 8 + q];
        const uint2* qp = queue + ((size_t)b * 8 + q) * QCAP2;
        for (int j = tid; j < cnt; j += 256) {
            uint2 e = qp[j];
            int slot = atomicAdd(&deg[e.x], 1);
            if (slot < CAP) bucket[e.x * CAP + slot] = (int)e.y;
            else {
                int p = atomicAdd(spill_cnt, 1);
                if (p < SPILL_MAX) { spill[2 * p] = (int)e.x; spill[2 * p + 1] = (int)e.y; }
            }
        }
    }
    // drain phase-A overflow (range-filtered so each edge lands exactly once); ~always empty
    int lo = q * NPX;
    int pc = *pspill_cnt; if (pc > PSPILL_MAX) pc = PSPILL_MAX;
    for (int j = sub * 256 + tid; j < pc; j += 256 * 256) {
        uint2 e = pspill[j];
        if ((unsigned)((int)e.x - lo) < NPX) {
            int slot = atomicAdd(&deg[e.x], 1);
            if (slot < CAP) bucket[e.x * CAP + slot] = (int)e.y;
            else {
                int p = atomicAdd(spill_cnt, 1);
                if (p < SPILL_MAX) { spill[2 * p] = (int)e.x; spill[2 * p + 1] = (int)e.y; }
            }
        }
    }
}

// ---------------- fp8 e4m3 encode/decode via HW cvt (gfx950) ----------------
__device__ __forceinline__ unsigned char enc_fp8(float f) {
    int w = __builtin_amdgcn_cvt_pk_fp8_f32(f, f, 0, false);
    return (unsigned char)(w & 0xFF);
}

// decode 8 fp8 (one uint2 = 8 bytes = lane's feature octet) and accumulate
__device__ __forceinline__ void acc_fp8(float acc[8], uint2 v) {
    floatx2 a0 = __builtin_amdgcn_cvt_pk_f32_fp8((int)v.x, false);
    floatx2 a1 = __builtin_amdgcn_cvt_pk_f32_fp8((int)v.x, true);
    floatx2 a2 = __builtin_amdgcn_cvt_pk_f32_fp8((int)v.y, false);
    floatx2 a3 = __builtin_amdgcn_cvt_pk_f32_fp8((int)v.y, true);
    acc[0] += a0.x; acc[1] += a0.y;
    acc[2] += a1.x; acc[3] += a1.y;
    acc[4] += a2.x; acc[5] += a2.y;
    acc[6] += a3.x; acc[7] += a3.y;
}

// ---------------- layer-0 matmul: u8 = fp8(din * (x @ W0)) ----------------
__global__ __launch_bounds__(256) void mm0_kernel(const float* __restrict__ in,
                                                  const float* __restrict__ W,
                                                  const int* __restrict__ deg,
                                                  unsigned char* __restrict__ u8) {
    __shared__ float Ws[64 * 64];
    __shared__ float hrow[4][64];
    int tid = threadIdx.x;
    {   // stage W (16 KB) via float4
        const float4* Wv = (const float4*)W;
        float4* Wsv = (float4*)Ws;
        #pragma unroll
        for (int i = 0; i < 4; ++i) Wsv[tid + 256 * i] = Wv[tid + 256 * i];
    }
    int local = tid >> 6;            // node within block
    int f = tid & 63;                // feature
    int n = blockIdx.x * 4 + local;  // NN divisible by 4
    float din = rsqrtf((float)(deg[n] + 1));
    hrow[local][f] = in[n * 64 + f];
    __syncthreads();
    float acc = 0.f;
    #pragma unroll
    for (int k = 0; k < 64; ++k)
        acc = fmaf(hrow[local][k], Ws[k * 64 + f], acc);
    u8[n * 64 + f] = enc_fp8(din * acc);
}

// ---------------- aggregation core, G=8 over fp8 rows (R12) ----------------
// wave = 8 edge-groups x 8 lanes; lane covers features [fo*8,fo*8+8) via one dwordx2
// (8B of fp8): per edge, 8 lanes span the 64B row = exactly one cache line. Bucket row
// (CAP=32, 128B) loaded unconditionally (deg load issues in parallel); 4 sweeps fully
// unrolled into independent accumulators. On exit acc[0..8) = aggregated row
// (self + neighbors), replicated across the 8 groups.
__device__ __forceinline__ void agg_row(const int* __restrict__ degv,
                                        const int* __restrict__ bucket,
                                        const uint2* __restrict__ u2,
                                        const int* __restrict__ spill,
                                        const int* __restrict__ spill_cnt,
                                        int n, int lane, int grp, int fo,
                                        float acc[8]) {
    float a1[8], a2[8], a3[8];
    #pragma unroll
    for (int i = 0; i < 8; ++i) { acc[i] = 0.f; a1[i] = 0.f; a2[i] = 0.f; a3[i] = 0.f; }
    int cidx = bucket[n * CAP + (lane & 31)];        // unconditional coalesced row load
    int deg = degv[n];                               // issues in parallel with row load
    int dc = deg < CAP ? deg : CAP;
    if (grp == 0) acc_fp8(acc, u2[n * 8 + fo]);      // self loop
    int s0 = __shfl(cidx, grp);                      // edges 0..7
    int s1 = __shfl(cidx, grp + 8);                  // edges 8..15
    int s2 = __shfl(cidx, grp + 16);                 // edges 16..23
    int s3 = __shfl(cidx, grp + 24);                 // edges 24..31
    if (grp < dc)      acc_fp8(acc, u2[s0 * 8 + fo]);
    if (grp + 8 < dc)  acc_fp8(a1, u2[s1 * 8 + fo]);
    if (grp + 16 < dc) acc_fp8(a2, u2[s2 * 8 + fo]);
    if (grp + 24 < dc) acc_fp8(a3, u2[s3 * 8 + fo]);
    if (deg > CAP) {                                 // spill drain: ~never (wave-uniform skip)
        int cnt = *spill_cnt; if (cnt > SPILL_MAX) cnt = SPILL_MAX;
        for (int e = 0; e < cnt; ++e) {
            if (spill[2 * e] == n && grp == 0)
                acc_fp8(a3, u2[spill[2 * e + 1] * 8 + fo]);
        }
    }
    #pragma unroll
    for (int i = 0; i < 8; ++i) {                    // merge sweeps + 8 groups
        float v = (acc[i] + a1[i]) + (a2[i] + a3[i]);
        v += __shfl_xor(v, 8);
        v += __shfl_xor(v, 16);
        v += __shfl_xor(v, 32);
        acc[i] = v;
    }
}

// ---------------- fused aggregate + finalize + next-layer matmul (R7/R11-proven) ------------
__global__ __launch_bounds__(256, 8) void aggmm_kernel(const int* __restrict__ degv,
                                                       const int* __restrict__ bucket,
                                                       const uint2* __restrict__ uin,
                                                       const int* __restrict__ spill,
                                                       const int* __restrict__ spill_cnt,
                                                       const float* __restrict__ bias,
                                                       const float* __restrict__ W,
                                                       unsigned char* __restrict__ uout) {
    __shared__ float Ws[64 * 64];
    __shared__ float hrow[4][64];
    int tid = threadIdx.x;
    {   // stage W (16 KB) via float4
        const float4* Wv = (const float4*)W;
        float4* Wsv = (float4*)Ws;
        #pragma unroll
        for (int i = 0; i < 4; ++i) Wsv[tid + 256 * i] = Wv[tid + 256 * i];
    }
    __syncthreads();
    int wid = tid >> 6;
    int lane = tid & 63;
    int grp = lane >> 3;
    int fo = lane & 7;
    int n = blockIdx.x * 4 + wid;                     // NN divisible by 4
    float acc[8];
    agg_row(degv, bucket, uin, spill, spill_cnt, n, lane, grp, fo, acc);
    float din = rsqrtf((float)(degv[n] + 1));
    if (grp == 0) {                                   // lanes 0..7 hold the full row
        float4 blo = ((const float4*)bias)[fo * 2];
        float4 bhi = ((const float4*)bias)[fo * 2 + 1];
        float4 lo, hi;
        lo.x = fmaxf(fmaf(din, acc[0], blo.x), 0.f);
        lo.y = fmaxf(fmaf(din, acc[1], blo.y), 0.f);
        lo.z = fmaxf(fmaf(din, acc[2], blo.z), 0.f);
        lo.w = fmaxf(fmaf(din, acc[3], blo.w), 0.f);
        hi.x = fmaxf(fmaf(din, acc[4], bhi.x), 0.f);
        hi.y = fmaxf(fmaf(din, acc[5], bhi.y), 0.f);
        hi.z = fmaxf(fmaf(din, acc[6], bhi.z), 0.f);
        hi.w = fmaxf(fmaf(din, acc[7], bhi.w), 0.f);
        ((float4*)hrow[wid])[fo * 2] = lo;            // t row -> per-wave LDS
        ((float4*)hrow[wid])[fo * 2 + 1] = hi;
    }
    // same-wave LDS RAW (write above, read below): in-order LDS + compiler lgkmcnt
    // ordering through the shared array; no barrier needed (R7-proven).
    float o = 0.f;
    const float4* hv = (const float4*)hrow[wid];
    #pragma unroll
    for (int k4 = 0; k4 < 16; ++k4) {
        float4 h = hv[k4];                            // broadcast read (all lanes same addr)
        int kb = k4 * 4;
        o = fmaf(h.x, Ws[(kb + 0) * 64 + lane], o);
        o = fmaf(h.y, Ws[(kb + 1) * 64 + lane], o);
        o = fmaf(h.z, Ws[(kb + 2) * 64 + lane], o);
        o = fmaf(h.w, Ws[(kb + 3) * 64 + lane], o);
    }
    uout[n * 64 + lane] = enc_fp8(din * o);
}

// ---------------- final aggregate + global pool: gp += din*agg ----------------
__global__ __launch_bounds__(256, 8) void aggpool_kernel(const int* __restrict__ degv,
                                                         const int* __restrict__ bucket,
                                                         const uint2* __restrict__ uin,
                                                         const int* __restrict__ spill,
                                                         const int* __restrict__ spill_cnt,
                                                         float* __restrict__ gp) {
    __shared__ float gpart[64];
    int tid = threadIdx.x;
    if (tid < 64) gpart[tid] = 0.f;
    __syncthreads();
    int lane = tid & 63;
    int grp = lane >> 3;
    int fo = lane & 7;
    int n = blockIdx.x * 4 + (tid >> 6);              // NN divisible by 4
    float acc[8];
    agg_row(degv, bucket, uin, spill, spill_cnt, n, lane, grp, fo, acc);
    if (grp == 0) {                                   // lanes 0..7 hold the full row
        float din = rsqrtf((float)(degv[n] + 1));
        #pragma unroll
        for (int i = 0; i < 8; ++i) atomicAdd(&gpart[fo * 8 + i], din * acc[i]);
    }
    __syncthreads();
    if (tid < 64) atomicAdd(&gp[(blockIdx.x & 63) * 64 + tid], gpart[tid]);
}

// ---------------- head: g = colsum(gp) + N*b2;  out = g @ Wl + bl ----------------
__global__ __launch_bounds__(64) void head_kernel(const float* __restrict__ gp,
                                                  const float* __restrict__ b2,
                                                  const float* __restrict__ Wl,
                                                  const float* __restrict__ bl,
                                                  float* __restrict__ out) {
    int t = threadIdx.x;  // one wave
    float s = 0.f;
    #pragma unroll 8
    for (int r = 0; r < 64; ++r) s += gp[r * 64 + t];
    float gf = s + (float)NN * b2[t];
    #pragma unroll
    for (int c = 0; c < 10; ++c) {
        float p = gf * Wl[t * 10 + c];
        #pragma unroll
        for (int off = 32; off > 0; off >>= 1) p += __shfl_down(p, off);
        if (t == 0) out[c] = p + bl[c];
    }
}

extern "C" void kernel_launch(void* const* d_in, const int* in_sizes, int n_in,
                              void* d_out, int out_size, void* d_ws, size_t ws_size,
                              hipStream_t stream) {
    const float* x  = (const float*)d_in[0];
    const int* eidx = (const int*)d_in[1];
    const int* esrc = eidx;        // edge_idx[0]
    const int* edst = eidx + NE;   // edge_idx[1]
    const float* W0 = (const float*)d_in[2];
    const float* b0 = (const float*)d_in[3];
    const float* W1 = (const float*)d_in[4];
    const float* b1 = (const float*)d_in[5];
    const float* W2 = (const float*)d_in[6];
    const float* b2 = (const float*)d_in[7];
    const float* Wl = (const float*)d_in[8];
    const float* bl = (const float*)d_in[9];
    float* out = (float*)d_out;

    // workspace layout (4-byte units); ua/ub/queue 8B-aligned (even float offsets)
    float* ws = (float*)d_ws;
    size_t off = 0;
    int*   deg    = (int*)(ws + off); off += NN;
    unsigned char* ua = (unsigned char*)(ws + off); off += (size_t)NN * 16;   // fp8 N*64 (6.4MB)
    unsigned char* ub = (unsigned char*)(ws + off); off += (size_t)NN * 16;   // fp8 N*64
    // control block (one memset): gp + counters + qcnt
    float* gp         =        ws + off;  off += 64 * 64;                     // 4096
    int*   spill_cnt  = (int*)(ws + off); off += 2;
    int*   pspill_cnt = (int*)(ws + off); off += 2;
    int*   qcnt       = (int*)(ws + off); off += (size_t)NBLK_A * 8;          // 9376
    size_t ctrl_ints  = 4096 + 4 + (size_t)NBLK_A * 8;
    int*   spill  = (int*)(ws + off); off += 2 * (size_t)SPILL_MAX;
    uint2* pspill = (uint2*)(ws + off); off += 2 * (size_t)PSPILL_MAX;
    uint2* queue  = (uint2*)(ws + off); off += 2 * (size_t)NBLK_A * 8 * QCAP2; // 16.8 MB
    int*   bucket = (int*)(ws + off); off += (size_t)NN * CAP;                 // 12.8 MB

    hipMemsetAsync(deg, 0, NN * sizeof(int), stream);
    hipMemsetAsync(gp, 0, ctrl_ints * sizeof(int), stream);   // gp + counters + qcnt

    // two-phase bucket build (normal dispatches: R5 proved coop launch breaks b&7->XCD)
    part2_kernel<<<NBLK_A, 256, 0, stream>>>(esrc, edst, queue, qcnt, pspill, pspill_cnt);
    fill2_kernel<<<2048, 256, 0, stream>>>(queue, qcnt, pspill, pspill_cnt,
                                           deg, bucket, spill, spill_cnt);

    // layer 0 matmul: ua = fp8(din*(x@W0))
    mm0_kernel<<<NN / 4, 256, 0, stream>>>(x, W0, deg, ua);
    // fused: agg(ua) + relu/bias(b0) + matmul(W1) -> ub
    aggmm_kernel<<<NN / 4, 256, 0, stream>>>(deg, bucket, (const uint2*)ua, spill, spill_cnt, b0, W1, ub);
    // fused: agg(ub) + relu/bias(b1) + matmul(W2) -> ua
    aggmm_kernel<<<NN / 4, 256, 0, stream>>>(deg, bucket, (const uint2*)ub, spill, spill_cnt, b1, W2, ua);
    // fused: agg(ua) + global pool (din folded; N*b2 added in head)
    aggpool_kernel<<<NN / 4, 256, 0, stream>>>(deg, bucket, (const uint2*)ua, spill, spill_cnt, gp);
    head_kernel<<<1, 64, 0, stream>>>(gp, b2, Wl, bl, out);
}